// Round 13
// baseline (184.895 us; speedup 1.0000x reference)
//
#include <hip/hip_runtime.h>
#include <math.h>

#define B 2
#define C 32
#define H 128
#define W 416
#define D 48
#define HW (H*W)
#define CHW (C*HW)
#define EPSN 1e-3f
#define ISCALE 0.05892556509887896f   // 1/sqrt(C*9)
#define ESTR 36     // k_e LDS stride (floats): stride-1 reads conflict-free
#define DSPL (D / 2)                   // disparities per z-block (24)

typedef _Float16 h16;
typedef _Float16 __attribute__((ext_vector_type(2))) h16x2;

__device__ __forceinline__ float clip10(float x) {
    return fminf(fmaxf(x, -10.0f), 10.0f);
}

__device__ __forceinline__ float fdot2(h16x2 a, h16x2 bb, float c) {
    return __builtin_amdgcn_fdot2(a, bb, c, false);
}
__device__ __forceinline__ h16x2 u2h(unsigned int u) {
    union { unsigned int u; h16x2 h; } cv; cv.u = u; return cv.h;
}
__device__ __forceinline__ unsigned int pkh(float a, float bb) {
    union { h16x2 h; unsigned int u; } cv;
    cv.h = h16x2{(h16)a, (h16)bb}; return cv.u;
}

#define FMA4(acc, f, k, u) acc += f[4*(k)+0]*(u).x + f[4*(k)+1]*(u).y \
                               + f[4*(k)+2]*(u).z + f[4*(k)+3]*(u).w;

#define CLW(v) ((v) < 0 ? 0 : ((v) > (W - 1) ? (W - 1) : (v)))

// ---------------------------------------------------------------------------
// k_norm: 3x3 zero-padded box of sql/sqr -> inverse patch norms inl/inr.
__global__ __launch_bounds__(256) void k_norm(const float* __restrict__ sql,
                                              const float* __restrict__ sqr,
                                              float* __restrict__ inl,
                                              float* __restrict__ inr) {
    int idx = blockIdx.x * 256 + threadIdx.x;
    if (idx >= B * HW) return;
    int b = idx / HW, hw = idx - b * HW;
    int h = hw / W, w = hw - h * W;
    float sl = 0.f, sr = 0.f;
#pragma unroll
    for (int di = -1; di <= 1; ++di) {
        int hh = h + di;
        if (hh < 0 || hh >= H) continue;
#pragma unroll
        for (int dj = -1; dj <= 1; ++dj) {
            int ww = w + dj;
            if (ww < 0 || ww >= W) continue;
            int p = b * HW + hh * W + ww;
            sl += sql[p];
            sr += sqr[p];
        }
    }
    inl[idx] = 1.0f / fmaxf(sqrtf(sl), EPSN);
    inr[idx] = 1.0f / fmaxf(sqrtf(sr), EPSN);
}

// ---------------------------------------------------------------------------
// stage_row_v2 (k_e): stage [C][W] row into LDS transposed [w][c], stride
// ESTR=36 (fp32).
__device__ __forceinline__ void stage_row_v2(const float* __restrict__ gsrc,
                                             float* __restrict__ lds,
                                             int tid, int nthreads) {
    for (int t = tid; t < (W / 4) * C; t += nthreads) {
        int rw = t & 7;
        int cl = (t >> 3) & 7;
        int g  = t >> 6;              // 0..51
        int wg = g % 13;
        int ch = g / 13;              // 0..3
        int c  = ch * 8 + cl;
        int w4 = (wg * 8 + rw) * 4;
        float4 v = *(const float4*)(gsrc + (size_t)c * HW + w4);
        lds[(w4 + 0) * ESTR + c] = v.x;
        lds[(w4 + 1) * ESTR + c] = v.y;
        lds[(w4 + 2) * ESTR + c] = v.z;
        lds[(w4 + 3) * ESTR + c] = v.w;
    }
}

// ---------------------------------------------------------------------------
// stage_row3_h (k_lr): stage VERTICAL 3-tap vsum as PACKED fp16 channel-pairs.
// Column v = 16 dwords, 64 B. Layout:
//   base dword  = 16 * (v ^ ((v>>1)&1))
//   phys dword  = 4*((dw>>2) ^ ky(v)) + (dw&3),  ky(v) = ((v>>1)^(v>>2))&3
// Reads (v = v0+2*lane): all 32 banks, 8 dwords/bank = structural min.
// Writes: 4-way on half the instructions ~ net free.
__device__ __forceinline__ void stage_row3_h(const float* __restrict__ gsrc,
                                             unsigned int* __restrict__ lds,
                                             int h, int tid, int nthreads) {
    for (int t = tid; t < (W / 4) * (C / 2); t += nthreads) {   // 1664 items
        int p = t & 15;               // channel pair 0..15
        int u = t >> 4;               // column quad 0..103
        int v0 = 4 * u;
        const float* pa = gsrc + (size_t)(2 * p) * HW + v0;
        const float* pb = pa + HW;
        float4 va = *(const float4*)pa;
        float4 vb = *(const float4*)pb;
        if (h > 0) {
            float4 xa = *(const float4*)(pa - W);
            float4 xb = *(const float4*)(pb - W);
            va.x += xa.x; va.y += xa.y; va.z += xa.z; va.w += xa.w;
            vb.x += xb.x; vb.y += xb.y; vb.z += xb.z; vb.w += xb.w;
        }
        if (h < H - 1) {
            float4 xa = *(const float4*)(pa + W);
            float4 xb = *(const float4*)(pb + W);
            va.x += xa.x; va.y += xa.y; va.z += xa.z; va.w += xa.w;
            vb.x += xb.x; vb.y += xb.y; vb.z += xb.z; vb.w += xb.w;
        }
        int q = p >> 2, lo = p & 3;
        unsigned int pk0 = pkh(va.x, vb.x);
        unsigned int pk1 = pkh(va.y, vb.y);
        unsigned int pk2 = pkh(va.z, vb.z);
        unsigned int pk3 = pkh(va.w, vb.w);
#define PUTH(vv, val) { int _v = (vv); \
    lds[16 * (_v ^ ((_v >> 1) & 1)) \
        + 4 * (q ^ ((((_v) >> 1) ^ ((_v) >> 2)) & 3)) + lo] = (val); }
        PUTH(v0 + 0, pk0)
        PUTH(v0 + 1, pk1)
        PUTH(v0 + 2, pk2)
        PUTH(v0 + 3, pk3)
#undef PUTH
    }
}

// ---------------------------------------------------------------------------
// k_lr: sL, sR AND sLR in one 768-thread block (12 waves), grid (H,B,2).
// Wave-groups: grp0 = L dot-loop, grp1 = R dot-loop, grp2 = LR2 (EH 3-tap,
// pure memory — co-schedules under grp0/1's VALU+LDS work; no extra launch).
// fp16 swizzled tiles + v_dot2 + register double-buffer as r12.
__global__ __launch_bounds__(768) void k_lr(const float* __restrict__ xm,
                                            const float* __restrict__ xl,
                                            const float* __restrict__ xr,
                                            const float* __restrict__ inl,
                                            const float* __restrict__ inr,
                                            const _Float16* __restrict__ EH,
                                            float* __restrict__ out) {
    __shared__ unsigned int sBuL[W * 16];   // 26624 B
    __shared__ unsigned int sBuR[W * 16];   // 26624 B
    __shared__ float sInL[W];               // 1664 B
    __shared__ float sInR[W];               // 1664 B
    int tid = threadIdx.x;
    int grp = tid >> 8;               // 0 = L, 1 = R, 2 = LR2
    int t8 = tid & 255;
    int h = blockIdx.x;
    int b = blockIdx.y;
    int d0 = blockIdx.z * DSPL;
    bool act = t8 < (W / 2);          // 208 active per group
    int w = 2 * t8;
    int bhw = b * HW + h * W;
    const float* pm = xm + (size_t)b * CHW + h * W;

    // fl for w and w+1, normalized, packed to fp16 channel-pairs (grp 0/1).
    h16x2 f0h[16], f1h[16];
    if (act && grp < 2) {
        float t0[C], t1[C];
        float am0 = 0.f, am1 = 0.f;
#pragma unroll
        for (int c = 0; c < C; ++c) {
            float2 mv = *(const float2*)(pm + (size_t)c * HW + w);
            t0[c] = mv.x; t1[c] = mv.y;
            am0 += mv.x * mv.x; am1 += mv.y * mv.y;
        }
        float im0 = 1.0f / fmaxf(sqrtf(am0), EPSN);
        float im1 = 1.0f / fmaxf(sqrtf(am1), EPSN);
#pragma unroll
        for (int j = 0; j < 16; ++j) {
            f0h[j] = h16x2{(h16)(t0[2 * j] * im0), (h16)(t0[2 * j + 1] * im0)};
            f1h[j] = h16x2{(h16)(t1[2 * j] * im1), (h16)(t1[2 * j + 1] * im1)};
        }
    } else {
#pragma unroll
        for (int j = 0; j < 16; ++j) { f0h[j] = h16x2{(h16)0.f, (h16)0.f};
                                       f1h[j] = h16x2{(h16)0.f, (h16)0.f}; }
    }

    // Stage both tiles + in-norm rows with all 768 threads, single barrier.
    stage_row3_h(xl + (size_t)b * CHW + h * W, sBuL, h, tid, 768);
    stage_row3_h(xr + (size_t)b * CHW + h * W, sBuR, h, tid, 768);
    for (int j = tid; j < W; j += 768) {
        sInL[j] = inl[bhw + j];
        sInR[j] = inr[bhw + j];
    }
    __syncthreads();

    uint4 RA0, RA1, RA2, RA3;
    uint4 RB0, RB1, RB2, RB3;

#define LOADH(P, buf, vv) { int _v = CLW(vv); \
    const uint4* _c4 = (const uint4*)((buf) + 16 * (_v ^ ((_v >> 1) & 1))); \
    int _ky = ((_v >> 1) ^ (_v >> 2)) & 3; \
    P##0 = _c4[_ky]; P##1 = _c4[1 ^ _ky]; P##2 = _c4[2 ^ _ky]; P##3 = _c4[3 ^ _ky]; }

#define DOTH(P, c0, c1) { \
    float _a0 = 0.f, _a1 = 0.f, _b0 = 0.f, _b1 = 0.f; \
    _a0 = fdot2(f0h[0],  u2h((P##0).x), _a0); _a0 = fdot2(f0h[1],  u2h((P##0).y), _a0); \
    _a0 = fdot2(f0h[2],  u2h((P##0).z), _a0); _a0 = fdot2(f0h[3],  u2h((P##0).w), _a0); \
    _a0 = fdot2(f0h[4],  u2h((P##1).x), _a0); _a0 = fdot2(f0h[5],  u2h((P##1).y), _a0); \
    _a0 = fdot2(f0h[6],  u2h((P##1).z), _a0); _a0 = fdot2(f0h[7],  u2h((P##1).w), _a0); \
    _a1 = fdot2(f0h[8],  u2h((P##2).x), _a1); _a1 = fdot2(f0h[9],  u2h((P##2).y), _a1); \
    _a1 = fdot2(f0h[10], u2h((P##2).z), _a1); _a1 = fdot2(f0h[11], u2h((P##2).w), _a1); \
    _a1 = fdot2(f0h[12], u2h((P##3).x), _a1); _a1 = fdot2(f0h[13], u2h((P##3).y), _a1); \
    _a1 = fdot2(f0h[14], u2h((P##3).z), _a1); _a1 = fdot2(f0h[15], u2h((P##3).w), _a1); \
    _b0 = fdot2(f1h[0],  u2h((P##0).x), _b0); _b0 = fdot2(f1h[1],  u2h((P##0).y), _b0); \
    _b0 = fdot2(f1h[2],  u2h((P##0).z), _b0); _b0 = fdot2(f1h[3],  u2h((P##0).w), _b0); \
    _b0 = fdot2(f1h[4],  u2h((P##1).x), _b0); _b0 = fdot2(f1h[5],  u2h((P##1).y), _b0); \
    _b0 = fdot2(f1h[6],  u2h((P##1).z), _b0); _b0 = fdot2(f1h[7],  u2h((P##1).w), _b0); \
    _b1 = fdot2(f1h[8],  u2h((P##2).x), _b1); _b1 = fdot2(f1h[9],  u2h((P##2).y), _b1); \
    _b1 = fdot2(f1h[10], u2h((P##2).z), _b1); _b1 = fdot2(f1h[11], u2h((P##2).w), _b1); \
    _b1 = fdot2(f1h[12], u2h((P##3).x), _b1); _b1 = fdot2(f1h[13], u2h((P##3).y), _b1); \
    _b1 = fdot2(f1h[14], u2h((P##3).z), _b1); _b1 = fdot2(f1h[15], u2h((P##3).w), _b1); \
    c0 = _a0 + _a1; c1 = _b0 + _b1; }

    if (act && grp == 0) {
        // ---- phase L: columns v = w+d0-1+j, j=0..26. Center m=v-1 done at
        // j>=2; store pairs (s0 from j-1, s1 from j) at j>=3, d = d0+j-3.
        float* oL = out + ((size_t)b * 3 + 0) * D * HW + h * W;
        const int vb = w + d0 - 1;
        float g0a = 0.f, g0b = 0.f, g1a = 0.f, g1b = 0.f, s0p = 0.f;
#define STEPL(P, jj) { int v = vb + (jj); bool ok = (v >= 0) && (v < W); \
    float c0, c1; DOTH(P, c0, c1); c0 = ok ? c0 : 0.f; c1 = ok ? c1 : 0.f; \
    float s0 = 0.f, s1 = 0.f; \
    if ((jj) >= 2) { int m = v - 1; \
        if (m < W) { float sc = sInL[m] * ISCALE; \
            s0 = clip10((g0a + g0b + c0) * sc); s1 = clip10((g1a + g1b + c1) * sc); } \
        if ((jj) >= 3) { int d = d0 + (jj) - 3; \
            *(float2*)(oL + (size_t)d * HW + w) = make_float2(s0p, s1); } } \
    s0p = s0; g0a = g0b; g0b = c0; g1a = g1b; g1b = c1; }
        LOADH(RA, sBuL, vb);
#pragma unroll 2
        for (int j = 0; j < DSPL + 2; j += 2) {   // steps 0..25; tail 26
            LOADH(RB, sBuL, vb + j + 1);
            STEPL(RA, j);
            LOADH(RA, sBuL, vb + j + 2);
            STEPL(RB, j + 1);
        }
        STEPL(RA, DSPL + 2);
#undef STEPL
    } else if (act && grp == 1) {
        // ---- phase R: columns v = w-d0-DSPL+j, j=0..26, ascending. Center
        // m=v-1 at j>=2; store pairs at j>=3 for d = d0+DSPL+2-j.
        float* oR = out + ((size_t)b * 3 + 1) * D * HW + h * W;
        const int vb = w - d0 - DSPL;
        float g0a = 0.f, g0b = 0.f, g1a = 0.f, g1b = 0.f, s0p = 0.f;
#define STEPR(P, jj) { int v = vb + (jj); bool ok = (v >= 0) && (v < W); \
    float c0, c1; DOTH(P, c0, c1); c0 = ok ? c0 : 0.f; c1 = ok ? c1 : 0.f; \
    float s0 = 0.f, s1 = 0.f; \
    if ((jj) >= 2) { int m = v - 1; \
        if (m >= 0) { float sc = sInR[m] * ISCALE; \
            s0 = clip10((g0a + g0b + c0) * sc); s1 = clip10((g1a + g1b + c1) * sc); } \
        if ((jj) >= 3) { int d = d0 + DSPL + 2 - (jj); \
            *(float2*)(oR + (size_t)d * HW + w) = make_float2(s0p, s1); } } \
    s0p = s0; g0a = g0b; g0b = c0; g1a = g1b; g1b = c1; }
        LOADH(RA, sBuR, vb);
#pragma unroll 2
        for (int j = 0; j < DSPL + 2; j += 2) {
            LOADH(RB, sBuR, vb + j + 1);
            STEPR(RA, j);
            LOADH(RA, sBuR, vb + j + 2);
            STEPR(RB, j + 1);
        }
        STEPR(RA, DSPL + 2);
#undef STEPR
    } else if (act) {
        // ---- group LR2: sLR = vertical 3-tap of fp16 EH at column vc=w-d,
        // times inverse norms (from sInL/sInR). Pure-memory; overlaps the
        // dot groups. Covers d = d0..d0+DSPL-1 for (w, w+1).
        float* oC = out + ((size_t)b * 3 + 2) * D * HW + h * W;
        bool hm = (h > 0), hp = (h < H - 1);
#pragma unroll 4
        for (int i = 0; i < DSPL; ++i) {
            int d = d0 + i;
            const _Float16* base = EH + ((size_t)b * D + d) * HW + h * W;
            float r0 = 0.f, r1 = 0.f;
            if (w >= d && w + d < W) {
                int vc = w - d;
                float e = (float)base[vc];
                if (hm) e += (float)base[vc - W];
                if (hp) e += (float)base[vc + W];
                r0 = clip10(e * sInL[w + d] * sInR[vc] * ISCALE);
            }
            int w1 = w + 1;
            if (w1 >= d && w1 + d < W) {
                int vc = w1 - d;
                float e = (float)base[vc];
                if (hm) e += (float)base[vc - W];
                if (hp) e += (float)base[vc + W];
                r1 = clip10(e * sInL[w1 + d] * sInR[vc] * ISCALE);
            }
            *(float2*)(oC + (size_t)d * HW + w) = make_float2(r0, r1);
        }
    }
#undef LOADH
#undef DOTH
}

// ---------------------------------------------------------------------------
// k_e: EH[b,d,h,v] = horizontal 3-tap of E, E[v] = sum_c xl[.,v+2d]*xr[.,v].
// r7 structure + register double-buffer; EH stored fp16. Plain
// __launch_bounds__(448): the old ",4" capped VGPR at 128 while the
// double-buffer needs ~130 — suspected silent spill.
__global__ __launch_bounds__(448) void k_e(const float* __restrict__ xl,
                                           const float* __restrict__ xr,
                                           _Float16* __restrict__ EH,
                                           float* __restrict__ sql,
                                           float* __restrict__ sqr) {
    __shared__ float sXL[W * ESTR];   // 59904 B
    int tid = threadIdx.x;
    int h = blockIdx.x;
    int b = blockIdx.y;
    int d0 = blockIdx.z * DSPL;
    int lane = tid & 63;
    int wv = tid >> 6;                // 0..6
    int v = wv * 62 + lane - 1;       // -1 .. 433
    bool vin = (v >= 0) && (v < W);
    const float* br = xr + (size_t)b * CHW + h * W;

    float xrv[C];
#pragma unroll
    for (int c = 0; c < C; ++c) xrv[c] = vin ? br[c * HW + v] : 0.0f;

    stage_row_v2(xl + (size_t)b * CHW + h * W, sXL, tid, 448);
    __syncthreads();

    bool wr = (lane >= 1) && (lane <= 62) && (v < W);   // v>=0 implied

    if (blockIdx.z == 0) {
        float sr_ = 0.f, sl_ = 0.f;
#pragma unroll
        for (int c = 0; c < C; ++c) sr_ += xrv[c] * xrv[c];
        if (vin) {
            const float4* c4 = (const float4*)(sXL + v * ESTR);
#pragma unroll
            for (int q = 0; q < 8; ++q) {
                float4 x = c4[q];
                sl_ += x.x * x.x + x.y * x.y + x.z * x.z + x.w * x.w;
            }
        }
        if (wr) {
            sqr[b * HW + h * W + v] = sr_;
            sql[b * HW + h * W + v] = sl_;
        }
    }

    _Float16* pe = EH + (((size_t)b * D) * H + h) * W + v;

    float4 RA0, RA1, RA2, RA3, RA4, RA5, RA6, RA7;
    float4 RB0, RB1, RB2, RB3, RB4, RB5, RB6, RB7;

#define LOADE(P, col) { int _vq = CLW(col); \
    const float4* _c4 = (const float4*)(sXL + (size_t)_vq * ESTR); \
    P##0 = _c4[0]; P##1 = _c4[1]; P##2 = _c4[2]; P##3 = _c4[3]; \
    P##4 = _c4[4]; P##5 = _c4[5]; P##6 = _c4[6]; P##7 = _c4[7]; }
#define STEPE(P, dd) { float _a = 0.f, _b = 0.f; \
    FMA4(_a, xrv, 0, P##0) FMA4(_a, xrv, 1, P##1) FMA4(_a, xrv, 2, P##2) FMA4(_a, xrv, 3, P##3) \
    FMA4(_b, xrv, 4, P##4) FMA4(_b, xrv, 5, P##5) FMA4(_b, xrv, 6, P##6) FMA4(_b, xrv, 7, P##7) \
    float e = (vin && (v + 2 * (dd)) < W) ? (_a + _b) : 0.f; \
    float em = __shfl_up(e, 1); \
    float ep = __shfl_down(e, 1); \
    float eh = em + e + ep; \
    if (wr) pe[(size_t)(dd) * HW] = (_Float16)eh; }

    LOADE(RA, v + 2 * d0);
#pragma unroll 2
    for (int d = d0; d < d0 + DSPL; d += 2) {
        LOADE(RB, v + 2 * d + 2);
        STEPE(RA, d);
        LOADE(RA, v + 2 * d + 4);
        STEPE(RB, d + 1);
    }
#undef LOADE
#undef STEPE
}

// ---------------------------------------------------------------------------
extern "C" void kernel_launch(void* const* d_in, const int* in_sizes, int n_in,
                              void* d_out, int out_size, void* d_ws, size_t ws_size,
                              hipStream_t stream) {
    const float* xl = (const float*)d_in[0];
    const float* xm = (const float*)d_in[1];
    const float* xr = (const float*)d_in[2];
    float* out = (float*)d_out;

    float* ws = (float*)d_ws;
    float* inl = ws;                               // B*HW
    float* inr = inl + B * HW;                     // B*HW
    float* sql = inr + B * HW;                     // B*HW
    float* sqr = sql + B * HW;                     // B*HW
    _Float16* EH = (_Float16*)(sqr + B * HW);      // B*D*H*W halfs

    k_e<<<dim3(H, B, 2), dim3(448), 0, stream>>>(xl, xr, EH, sql, sqr);
    k_norm<<<dim3((B * HW + 255) / 256), dim3(256), 0, stream>>>(sql, sqr, inl, inr);
    k_lr<<<dim3(H, B, 2), dim3(768), 0, stream>>>(xm, xl, xr, inl, inr, EH, out);
}